// Round 1
// baseline (1161.250 us; speedup 1.0000x reference)
//
#include <hip/hip_runtime.h>

#define N_GENES 2000
#define HID 128

typedef __attribute__((ext_vector_type(8))) short frag8;
typedef __attribute__((ext_vector_type(4))) float facc4;

static __device__ __forceinline__ unsigned short f2bf(float f) {
    unsigned int u = __float_as_uint(f);
    unsigned int r = (u + 0x7FFFu + ((u >> 16) & 1u)) >> 16;
    return (unsigned short)r;
}

// ---------------- transpose+convert weight: W[K][128] f32 -> Bt[128][Kpad] bf16 (zero-padded) ----------
__global__ void transpose_bt(const float* __restrict__ W, unsigned short* __restrict__ Bt,
                             int K, int Kpad) {
    int idx = blockIdx.x * blockDim.x + threadIdx.x;
    if (idx >= 128 * Kpad) return;
    int nrow = idx / Kpad, k = idx - nrow * Kpad;
    unsigned short v = 0;
    if (k < K) v = f2bf(W[(size_t)k * 128 + nrow]);
    Bt[idx] = v;
}

// ---------------- GEMM: C[M][128] = A[M][K] @ W  via Bt[n][k] bf16. 128x128 tile, 4 waves ----------
#define SA 72  // padded LDS stride (bf16 elems): 144B -> 2-way bank conflict only (free)

template <int AF32>
__global__ __launch_bounds__(256) void gemm_k(const void* __restrict__ Av,
                                              const unsigned short* __restrict__ Bt,
                                              const float* __restrict__ bias,
                                              float* __restrict__ Cf,
                                              unsigned short* __restrict__ Cb,
                                              int M, int K, int Kpad) {
    __shared__ __align__(16) unsigned short lA[128 * SA];
    __shared__ __align__(16) unsigned short lB[128 * SA];
    int t = threadIdx.x;
    int lane = t & 63, wv = t >> 6;
    int wr = wv >> 1, wc = wv & 1;
    int lr = lane & 15, lq = lane >> 4;
    facc4 acc[4][4];
#pragma unroll
    for (int i = 0; i < 4; i++)
#pragma unroll
        for (int j = 0; j < 4; j++) acc[i][j] = (facc4){0.f, 0.f, 0.f, 0.f};
    int row_base = blockIdx.x * 128;
    int sr = t >> 1;
    int sc0 = (t & 1) * 32;
    int rg = row_base + sr;

    for (int k0 = 0; k0 < Kpad; k0 += 64) {
        __syncthreads();
        if (AF32) {
            const float* A = (const float*)Av;
            const float* arow = A + (size_t)rg * K + k0 + sc0;
#pragma unroll
            for (int i = 0; i < 8; i++) {
                int kk = k0 + sc0 + i * 4;
                float4 v = {0.f, 0.f, 0.f, 0.f};
                if (rg < M && kk < K) v = *(const float4*)(arow + i * 4);
                ushort4 b;
                b.x = f2bf(v.x); b.y = f2bf(v.y); b.z = f2bf(v.z); b.w = f2bf(v.w);
                *(ushort4*)&lA[sr * SA + sc0 + i * 4] = b;
            }
        } else {
            const unsigned short* A = (const unsigned short*)Av;
            const unsigned short* arow = A + (size_t)rg * K + k0 + sc0;
#pragma unroll
            for (int i = 0; i < 4; i++) {
                uint4 v = {0u, 0u, 0u, 0u};
                if (rg < M) v = *(const uint4*)(arow + i * 8);
                *(uint4*)&lA[sr * SA + sc0 + i * 8] = v;
            }
        }
        {
            const unsigned short* brow = Bt + (size_t)sr * Kpad + k0 + sc0;
#pragma unroll
            for (int i = 0; i < 4; i++)
                *(uint4*)&lB[sr * SA + sc0 + i * 8] = *(const uint4*)(brow + i * 8);
        }
        __syncthreads();
#pragma unroll
        for (int ks = 0; ks < 2; ks++) {
            frag8 af[4], bf[4];
#pragma unroll
            for (int mi = 0; mi < 4; mi++)
                af[mi] = *(const frag8*)&lA[(wr * 64 + mi * 16 + lr) * SA + ks * 32 + lq * 8];
#pragma unroll
            for (int ni = 0; ni < 4; ni++)
                bf[ni] = *(const frag8*)&lB[(wc * 64 + ni * 16 + lr) * SA + ks * 32 + lq * 8];
#pragma unroll
            for (int mi = 0; mi < 4; mi++)
#pragma unroll
                for (int ni = 0; ni < 4; ni++)
                    acc[mi][ni] = __builtin_amdgcn_mfma_f32_16x16x32_bf16(af[mi], bf[ni], acc[mi][ni], 0, 0, 0);
        }
    }
#pragma unroll
    for (int mi = 0; mi < 4; mi++) {
#pragma unroll
        for (int r = 0; r < 4; r++) {
            int row = row_base + wr * 64 + mi * 16 + lq * 4 + r;
            if (row < M) {
#pragma unroll
                for (int ni = 0; ni < 4; ni++) {
                    int col = wc * 64 + ni * 16 + lr;
                    float v = acc[mi][ni][r];
                    if (bias) v += bias[col];
                    if (Cf) Cf[(size_t)row * 128 + col] = v;
                    if (Cb) Cb[(size_t)row * 128 + col] = f2bf(v);
                }
            }
        }
    }
}

// ---------------- CSR build ----------------
__global__ void deg_kernel(const int* __restrict__ dst, int* __restrict__ deg, int E) {
    int e = blockIdx.x * blockDim.x + threadIdx.x;
    if (e < E) atomicAdd(&deg[dst[e]], 1);
}

__global__ __launch_bounds__(1024) void scan_excl(const int* __restrict__ in, int* __restrict__ out, int n) {
    __shared__ int buf[1024];
    __shared__ int carry_s;
    int t = threadIdx.x;
    if (t == 0) carry_s = 0;
    __syncthreads();
    for (int base = 0; base < n; base += 4096) {
        int i0 = base + t * 4;
        int a = 0, b = 0, c = 0, d = 0;
        if (i0 + 3 < n) {
            int4 v = *(const int4*)(in + i0);
            a = v.x; b = v.y; c = v.z; d = v.w;
        } else {
            if (i0 < n) a = in[i0];
            if (i0 + 1 < n) b = in[i0 + 1];
            if (i0 + 2 < n) c = in[i0 + 2];
        }
        int s4 = a + b + c + d;
        int x = s4;
        buf[t] = x;
        __syncthreads();
        for (int off = 1; off < 1024; off <<= 1) {
            int y = (t >= off) ? buf[t - off] : 0;
            __syncthreads();
            x += y;
            buf[t] = x;
            __syncthreads();
        }
        int total = buf[1023];
        int excl = carry_s + x - s4;
        if (i0 < n) out[i0] = excl;
        if (i0 + 1 < n) out[i0 + 1] = excl + a;
        if (i0 + 2 < n) out[i0 + 2] = excl + a + b;
        if (i0 + 3 < n) out[i0 + 3] = excl + a + b + c;
        __syncthreads();
        if (t == 0) carry_s += total;
        __syncthreads();
    }
    if (t == 0) out[n] = carry_s;
}

__global__ void fill_kernel(const int* __restrict__ dst, const int* __restrict__ offs,
                            int* __restrict__ cur, int* __restrict__ eids, int E) {
    int e = blockIdx.x * blockDim.x + threadIdx.x;
    if (e < E) {
        int d = dst[e];
        int p = offs[d] + atomicAdd(&cur[d], 1);
        eids[p] = e;
    }
}

// ---------------- GAT: one wave per dst node, online softmax, no atomics ----------------
__global__ __launch_bounds__(256) void gat_kernel(const int* __restrict__ offs,
                                                  const int* __restrict__ eids,
                                                  const int* __restrict__ src_idx,
                                                  const float* __restrict__ ew,
                                                  const float* __restrict__ hs,
                                                  const float* __restrict__ hd,
                                                  const float* __restrict__ wedge,
                                                  const float* __restrict__ attn,
                                                  const float* __restrict__ bias,
                                                  float* __restrict__ out, int n) {
    int node = blockIdx.x * 4 + (threadIdx.x >> 6);
    if (node >= n) return;
    int lane = threadIdx.x & 63;
    const float wv0 = wedge[lane], wv1 = wedge[lane + 64];
    const float a0 = attn[lane], a1 = attn[lane + 64];
    const float hd0 = hd[(size_t)node * 128 + lane];
    const float hd1 = hd[(size_t)node * 128 + 64 + lane];
    int s = offs[node], cnt = offs[node + 1] - s;
    float m0 = -INFINITY, l0 = 0.f, acc0 = 0.f;
    float m1 = -INFINITY, l1 = 0.f, acc1 = 0.f;
    int e = 0, src = 0;
    float w = 0.f;
    if (cnt > 0) {
        e = eids[s];
        src = src_idx[e];
        w = ew[e];
    }
    for (int i = 0; i < cnt; i++) {
        int e_n = 0, src_n = 0;
        float w_n = 0.f;
        if (i + 1 < cnt) {
            e_n = eids[s + i + 1];
            src_n = src_idx[e_n];
            w_n = ew[e_n];
        }
        float hs0 = hs[(size_t)src * 128 + lane];
        float hs1 = hs[(size_t)src * 128 + 64 + lane];
        float z0 = hs0 + hd0 + w * wv0; z0 = (z0 > 0.f) ? z0 : 0.2f * z0;
        float z1 = hs1 + hd1 + w * wv1; z1 = (z1 > 0.f) ? z1 : 0.2f * z1;
        float t0 = z0 * a0, t1 = z1 * a1;
#pragma unroll
        for (int o = 16; o >= 1; o >>= 1) {
            t0 += __shfl_xor(t0, o);
            t1 += __shfl_xor(t1, o);
        }
        float mn0 = fmaxf(m0, t0), mn1 = fmaxf(m1, t1);
        float sc0 = __expf(m0 - mn0), sc1 = __expf(m1 - mn1);
        float p0 = __expf(t0 - mn0), p1 = __expf(t1 - mn1);
        l0 = l0 * sc0 + p0; acc0 = acc0 * sc0 + p0 * hs0; m0 = mn0;
        l1 = l1 * sc1 + p1; acc1 = acc1 * sc1 + p1 * hs1; m1 = mn1;
        e = e_n; src = src_n; w = w_n;
    }
    out[(size_t)node * 128 + lane] = acc0 / (l0 + 1e-16f) + bias[lane];
    out[(size_t)node * 128 + 64 + lane] = acc1 / (l1 + 1e-16f) + bias[lane + 64];
}

// ---------------- combine + ELU + LayerNorm (in-place on d_out which holds h_pruned) ----------
__global__ __launch_bounds__(256) void final_kernel(const float* __restrict__ hf,
                                                    float* __restrict__ out,
                                                    const float* __restrict__ alpha_p,
                                                    const float* __restrict__ scale,
                                                    const float* __restrict__ beta, int n) {
    int node = blockIdx.x * 4 + (threadIdx.x >> 6);
    if (node >= n) return;
    int lane = threadIdx.x & 63;
    float a = *alpha_p;
    float f0 = hf[(size_t)node * 128 + lane], f1 = hf[(size_t)node * 128 + 64 + lane];
    float p0 = out[(size_t)node * 128 + lane], p1 = out[(size_t)node * 128 + 64 + lane];
    float x0 = (1.f - a) * f0 + a * p0;
    float x1 = (1.f - a) * f1 + a * p1;
    x0 = (x0 > 0.f) ? x0 : expm1f(x0);
    x1 = (x1 > 0.f) ? x1 : expm1f(x1);
    float s = x0 + x1;
#pragma unroll
    for (int o = 32; o >= 1; o >>= 1) s += __shfl_xor(s, o);
    float mu = s * (1.f / 128.f);
    float d0 = x0 - mu, d1 = x1 - mu;
    float v = d0 * d0 + d1 * d1;
#pragma unroll
    for (int o = 32; o >= 1; o >>= 1) v += __shfl_xor(v, o);
    float rstd = rsqrtf(v * (1.f / 128.f) + 1e-6f);
    out[(size_t)node * 128 + lane] = d0 * rstd * scale[lane] + beta[lane];
    out[(size_t)node * 128 + 64 + lane] = d1 * rstd * scale[lane + 64] + beta[lane + 64];
}

extern "C" void kernel_launch(void* const* d_in, const int* in_sizes, int n_in,
                              void* d_out, int out_size, void* d_ws, size_t ws_size,
                              hipStream_t stream) {
    const float* nf = (const float*)d_in[0];
    const int* fei = (const int*)d_in[1];
    const float* few = (const float*)d_in[2];
    const int* pei = (const int*)d_in[3];
    const float* pew = (const float*)d_in[4];
    const float* alpha = (const float*)d_in[5];
    const float* ip_w = (const float*)d_in[6];
    const float* ip_b = (const float*)d_in[7];
    const float* gf_wsrc = (const float*)d_in[8];
    const float* gf_wdst = (const float*)d_in[9];
    const float* gf_wedge = (const float*)d_in[10];
    const float* gf_attn = (const float*)d_in[11];
    const float* gf_bias = (const float*)d_in[12];
    const float* gp_wsrc = (const float*)d_in[13];
    const float* gp_wdst = (const float*)d_in[14];
    const float* gp_wedge = (const float*)d_in[15];
    const float* gp_attn = (const float*)d_in[16];
    const float* gp_bias = (const float*)d_in[17];
    const float* ln_scale = (const float*)d_in[18];
    const float* ln_bias = (const float*)d_in[19];

    const int N = in_sizes[0] / N_GENES;
    const int Ef = in_sizes[1] / 2;
    const int Ep = in_sizes[3] / 2;
    const int Kpad1 = 2048;

    // workspace carve
    char* base = (char*)d_ws;
    size_t off = 0;
    auto carve = [&](size_t bytes) -> char* {
        char* p = base + off;
        off = (off + bytes + 255) & ~(size_t)255;
        return p;
    };
    unsigned short* Bt1 = (unsigned short*)carve((size_t)128 * Kpad1 * 2);
    unsigned short* BtSf = (unsigned short*)carve(128 * 128 * 2);
    unsigned short* BtDf = (unsigned short*)carve(128 * 128 * 2);
    unsigned short* BtSp = (unsigned short*)carve(128 * 128 * 2);
    unsigned short* BtDp = (unsigned short*)carve(128 * 128 * 2);
    unsigned short* h_bf = (unsigned short*)carve((size_t)N * 128 * 2);
    float* hs = (float*)carve((size_t)N * 128 * 4);
    float* hd = (float*)carve((size_t)N * 128 * 4);
    float* h_full = (float*)carve((size_t)N * 128 * 4);
    int* deg = (int*)carve((size_t)N * 4);
    int* offs = (int*)carve((size_t)(N + 4) * 4);
    int* cur = (int*)carve((size_t)N * 4);
    int* eids = (int*)carve((size_t)(Ef > Ep ? Ef : Ep) * 4);
    float* out_f = (float*)d_out;

    // weight prep
    transpose_bt<<<(128 * Kpad1 + 255) / 256, 256, 0, stream>>>(ip_w, Bt1, N_GENES, Kpad1);
    transpose_bt<<<64, 256, 0, stream>>>(gf_wsrc, BtSf, 128, 128);
    transpose_bt<<<64, 256, 0, stream>>>(gf_wdst, BtDf, 128, 128);
    transpose_bt<<<64, 256, 0, stream>>>(gp_wsrc, BtSp, 128, 128);
    transpose_bt<<<64, 256, 0, stream>>>(gp_wdst, BtDp, 128, 128);

    int gblocks = (N + 127) / 128;
    // h = nf @ ip_w + ip_b  -> bf16
    gemm_k<1><<<gblocks, 256, 0, stream>>>(nf, Bt1, ip_b, nullptr, h_bf, N, N_GENES, Kpad1);

    int nodeblocks = (N + 3) / 4;
    for (int g = 0; g < 2; g++) {
        const int* ei = g == 0 ? fei : pei;
        const float* ewp = g == 0 ? few : pew;
        const unsigned short* BtS = g == 0 ? BtSf : BtSp;
        const unsigned short* BtD = g == 0 ? BtDf : BtDp;
        const float* wedge = g == 0 ? gf_wedge : gp_wedge;
        const float* attn = g == 0 ? gf_attn : gp_attn;
        const float* bias = g == 0 ? gf_bias : gp_bias;
        float* outg = g == 0 ? h_full : out_f;
        int E = g == 0 ? Ef : Ep;
        const int* src = ei;
        const int* dst = ei + E;

        gemm_k<0><<<gblocks, 256, 0, stream>>>(h_bf, BtS, nullptr, hs, nullptr, N, 128, 128);
        gemm_k<0><<<gblocks, 256, 0, stream>>>(h_bf, BtD, nullptr, hd, nullptr, N, 128, 128);

        hipMemsetAsync(deg, 0, (size_t)N * 4, stream);
        deg_kernel<<<(E + 255) / 256, 256, 0, stream>>>(dst, deg, E);
        scan_excl<<<1, 1024, 0, stream>>>(deg, offs, N);
        hipMemsetAsync(cur, 0, (size_t)N * 4, stream);
        fill_kernel<<<(E + 255) / 256, 256, 0, stream>>>(dst, offs, cur, eids, E);

        gat_kernel<<<nodeblocks, 256, 0, stream>>>(offs, eids, src, ewp, hs, hd,
                                                   wedge, attn, bias, outg, N);
    }

    final_kernel<<<nodeblocks, 256, 0, stream>>>(h_full, out_f, alpha, ln_scale, ln_bias, N);
    (void)ws_size; (void)n_in; (void)out_size;
}

// Round 2
// 972.947 us; speedup vs baseline: 1.1935x; 1.1935x over previous
//
#include <hip/hip_runtime.h>

#define N_GENES 2000

typedef __attribute__((ext_vector_type(8))) short frag8;
typedef __attribute__((ext_vector_type(4))) float facc4;

static __device__ __forceinline__ unsigned short f2bf(float f) {
    unsigned int u = __float_as_uint(f);
    unsigned int r = (u + 0x7FFFu + ((u >> 16) & 1u)) >> 16;
    return (unsigned short)r;
}
static __device__ __forceinline__ float bf2f(unsigned short s) {
    return __uint_as_float(((unsigned int)s) << 16);
}

// ---- ip_w [K][128] f32 -> Bt [128][Kpad] bf16 (zero-padded) ----
__global__ void transpose_bt(const float* __restrict__ W, unsigned short* __restrict__ Bt,
                             int K, int Kpad) {
    int idx = blockIdx.x * blockDim.x + threadIdx.x;
    if (idx >= 128 * Kpad) return;
    int nrow = idx / Kpad, k = idx - nrow * Kpad;
    unsigned short v = 0;
    if (k < K) v = f2bf(W[(size_t)k * 128 + nrow]);
    Bt[idx] = v;
}

// ---- [wsrc|wdst] per graph -> Bcomb [256][128] bf16 ----
__global__ void transpose_small(const float* __restrict__ ws_f, const float* __restrict__ wd_f,
                                const float* __restrict__ ws_p, const float* __restrict__ wd_p,
                                unsigned short* __restrict__ Bf, unsigned short* __restrict__ Bp) {
    int idx = blockIdx.x * blockDim.x + threadIdx.x;
    if (idx >= 2 * 256 * 128) return;
    int g = idx >> 15;
    int r = (idx >> 7) & 255;
    int k = idx & 127;
    const float* w = (g == 0) ? (r < 128 ? ws_f : wd_f) : (r < 128 ? ws_p : wd_p);
    unsigned short v = f2bf(w[k * 128 + (r & 127)]);
    (g == 0 ? Bf : Bp)[(r << 7) | k] = v;
}

// ---- GEMM: 64-row x NT-col tile, 256 thr (4 waves), bf16 MFMA, bf16 out ----
#define SA 72

template <int AF32, int NT, int BIAS>
__global__ __launch_bounds__(256) void gemm64(const void* __restrict__ Av,
                                              const unsigned short* __restrict__ Bt,
                                              const float* __restrict__ bias,
                                              unsigned short* __restrict__ Cb,
                                              int M, int K, int Kpad) {
    __shared__ __align__(16) unsigned short lA[64 * SA];
    __shared__ __align__(16) unsigned short lB[NT * SA];
    constexpr int CF = NT / 64;
    int t = threadIdx.x, lane = t & 63, wv = t >> 6;
    int lr = lane & 15, lq = lane >> 4;
    facc4 acc[4][CF];
#pragma unroll
    for (int i = 0; i < 4; i++)
#pragma unroll
        for (int j = 0; j < CF; j++) acc[i][j] = (facc4){0.f, 0.f, 0.f, 0.f};
    int row_base = blockIdx.x * 64;

    for (int k0 = 0; k0 < Kpad; k0 += 64) {
        __syncthreads();
        if (AF32) {
            const float* A = (const float*)Av;
#pragma unroll
            for (int j = 0; j < 4; j++) {
                int q = j * 256 + t;
                int r = q >> 4, off = (q & 15) * 4;
                int rg = row_base + r; if (rg >= M) rg = M - 1;
                int kk = k0 + off;
                float4 v = {0.f, 0.f, 0.f, 0.f};
                if (kk < K) v = *(const float4*)(A + (size_t)rg * K + kk);
                ushort4 b;
                b.x = f2bf(v.x); b.y = f2bf(v.y); b.z = f2bf(v.z); b.w = f2bf(v.w);
                *(ushort4*)&lA[r * SA + off] = b;
            }
        } else {
            const unsigned short* A = (const unsigned short*)Av;
#pragma unroll
            for (int j = 0; j < 2; j++) {
                int q = j * 256 + t;
                int r = q >> 3, off = (q & 7) * 8;
                int rg = row_base + r; if (rg >= M) rg = M - 1;
                *(uint4*)&lA[r * SA + off] = *(const uint4*)(A + (size_t)rg * K + k0 + off);
            }
        }
#pragma unroll
        for (int j = 0; j < NT / 32; j++) {
            int q = j * 256 + t;
            int r = q >> 3, off = (q & 7) * 8;
            *(uint4*)&lB[r * SA + off] = *(const uint4*)(Bt + (size_t)r * Kpad + k0 + off);
        }
        __syncthreads();
#pragma unroll
        for (int ks = 0; ks < 2; ks++) {
            frag8 af[4], bf[CF];
#pragma unroll
            for (int mi = 0; mi < 4; mi++)
                af[mi] = *(const frag8*)&lA[(mi * 16 + lr) * SA + ks * 32 + lq * 8];
#pragma unroll
            for (int ni = 0; ni < CF; ni++)
                bf[ni] = *(const frag8*)&lB[(wv * 16 * CF + ni * 16 + lr) * SA + ks * 32 + lq * 8];
#pragma unroll
            for (int mi = 0; mi < 4; mi++)
#pragma unroll
                for (int ni = 0; ni < CF; ni++)
                    acc[mi][ni] = __builtin_amdgcn_mfma_f32_16x16x32_bf16(af[mi], bf[ni], acc[mi][ni], 0, 0, 0);
        }
    }
#pragma unroll
    for (int mi = 0; mi < 4; mi++) {
#pragma unroll
        for (int r = 0; r < 4; r++) {
            int row = row_base + mi * 16 + lq * 4 + r;
            if (row < M) {
#pragma unroll
                for (int ni = 0; ni < CF; ni++) {
                    int col = wv * 16 * CF + ni * 16 + lr;
                    float v = acc[mi][ni][r];
                    if (BIAS) v += bias[col];
                    Cb[(size_t)row * NT + col] = f2bf(v);
                }
            }
        }
    }
}

// ---- degree histogram for both graphs into deg[2N] ----
__global__ void deg2(const int* __restrict__ dst_f, int Ef,
                     const int* __restrict__ dst_p, int Ep,
                     int* __restrict__ deg, int N) {
    int e = blockIdx.x * blockDim.x + threadIdx.x;
    if (e < Ef) atomicAdd(&deg[dst_f[e]], 1);
    else if (e < Ef + Ep) atomicAdd(&deg[N + dst_p[e - Ef]], 1);
}

// ---- hierarchical exclusive scan: part sums -> top scan -> final ----
__global__ __launch_bounds__(256) void scan_part(const int* __restrict__ in,
                                                 int* __restrict__ bsum, int n) {
    int t = threadIdx.x, b = blockIdx.x;
    int lane = t & 63, wv = t >> 6;
    int base = b * 2048 + t * 8;
    int s = 0;
    if (base + 7 < n) {
        int4 v0 = *(const int4*)(in + base);
        int4 v1 = *(const int4*)(in + base + 4);
        s = v0.x + v0.y + v0.z + v0.w + v1.x + v1.y + v1.z + v1.w;
    } else {
#pragma unroll
        for (int j = 0; j < 8; j++) if (base + j < n) s += in[base + j];
    }
#pragma unroll
    for (int o = 32; o >= 1; o >>= 1) s += __shfl_xor(s, o);
    __shared__ int red[4];
    if (lane == 0) red[wv] = s;
    __syncthreads();
    if (t == 0) bsum[b] = red[0] + red[1] + red[2] + red[3];
}

__global__ __launch_bounds__(256) void scan_tops(int* __restrict__ bsum, int nb,
                                                 int* __restrict__ offs, int n) {
    __shared__ int buf[256];
    int t = threadIdx.x;
    int orig = (t < nb) ? bsum[t] : 0;
    int v = orig;
    buf[t] = v;
    __syncthreads();
    for (int o = 1; o < 256; o <<= 1) {
        int y = (t >= o) ? buf[t - o] : 0;
        __syncthreads();
        v += y;
        buf[t] = v;
        __syncthreads();
    }
    if (t < nb) bsum[t] = v - orig;
    if (t == nb - 1) offs[n] = v;
}

__global__ __launch_bounds__(256) void scan_final(const int* __restrict__ in,
                                                  const int* __restrict__ bsum,
                                                  int* __restrict__ offs, int n) {
    int t = threadIdx.x, b = blockIdx.x;
    int lane = t & 63, wv = t >> 6;
    int base = b * 2048 + t * 8;
    int a[8];
#pragma unroll
    for (int j = 0; j < 8; j++) a[j] = (base + j < n) ? in[base + j] : 0;
    int s = a[0] + a[1] + a[2] + a[3] + a[4] + a[5] + a[6] + a[7];
    int incl = s;
#pragma unroll
    for (int o = 1; o < 64; o <<= 1) {
        int y = __shfl_up(incl, o);
        if (lane >= o) incl += y;
    }
    __shared__ int wsum[4];
    if (lane == 63) wsum[wv] = incl;
    __syncthreads();
    int wpre = 0;
#pragma unroll
    for (int j = 0; j < 4; j++) if (j < wv) wpre += wsum[j];
    int excl = incl - s + wpre + bsum[b];
#pragma unroll
    for (int j = 0; j < 8; j++) {
        if (base + j < n) offs[base + j] = excl;
        excl += a[j];
    }
}

// ---- fill CSR-ordered src/weight arrays for both graphs ----
__global__ void fill2(const int* __restrict__ src_f, const int* __restrict__ dst_f,
                      const float* __restrict__ ew_f, int Ef,
                      const int* __restrict__ src_p, const int* __restrict__ dst_p,
                      const float* __restrict__ ew_p, int Ep,
                      const int* __restrict__ offs, int* __restrict__ cur,
                      int* __restrict__ srcs, float* __restrict__ ws, int N) {
    int e = blockIdx.x * blockDim.x + threadIdx.x;
    if (e >= Ef + Ep) return;
    int g = (e >= Ef);
    int ee = g ? e - Ef : e;
    int d = g ? dst_p[ee] : dst_f[ee];
    int node = g ? N + d : d;
    int p = offs[node] + atomicAdd(&cur[node], 1);
    srcs[p] = g ? src_p[ee] : src_f[ee];
    ws[p] = g ? ew_p[ee] : ew_f[ee];
}

// ---- GAT: one wave per dst node, online softmax, 3-slot pipelined gathers ----
__global__ __launch_bounds__(256) void gat_kernel(const int* __restrict__ offs,
                                                  const int* __restrict__ srcs,
                                                  const float* __restrict__ ws,
                                                  const unsigned short* __restrict__ hshd,
                                                  const float* __restrict__ wedge,
                                                  const float* __restrict__ attn,
                                                  const float* __restrict__ bias,
                                                  float* __restrict__ out, int n) {
    int node = blockIdx.x * 4 + (threadIdx.x >> 6);
    if (node >= n) return;
    int lane = threadIdx.x & 63;
    const float wv0 = wedge[lane], wv1 = wedge[lane + 64];
    const float a0 = attn[lane], a1 = attn[lane + 64];
    const unsigned short* hdrow = hshd + (size_t)node * 256 + 128;
    const float hd0 = bf2f(hdrow[lane]);
    const float hd1 = bf2f(hdrow[lane + 64]);
    int s = offs[node], cnt = offs[node + 1] - s;
    float m0 = -INFINITY, l0 = 0.f, acc0 = 0.f;
    float m1 = -INFINITY, l1 = 0.f, acc1 = 0.f;
    if (cnt > 0) {
        int last = s + cnt - 1;
        int jB = (s + 1 <= last) ? s + 1 : last;
        int srcA = srcs[s];       float wA = ws[s];
        int srcB = srcs[jB];      float wB = ws[jB];
        float hsA0 = bf2f(hshd[(size_t)srcA * 256 + lane]);
        float hsA1 = bf2f(hshd[(size_t)srcA * 256 + 64 + lane]);
        float hsB0 = bf2f(hshd[(size_t)srcB * 256 + lane]);
        float hsB1 = bf2f(hshd[(size_t)srcB * 256 + 64 + lane]);
        for (int i = 0; i < cnt; i++) {
            // prefetch slot C (2 ahead)
            int jC = s + i + 2; if (jC > last) jC = last;
            int srcC = srcs[jC];  float wC = ws[jC];
            float hsC0 = bf2f(hshd[(size_t)srcC * 256 + lane]);
            float hsC1 = bf2f(hshd[(size_t)srcC * 256 + 64 + lane]);
            // compute on slot A
            float z0 = hsA0 + hd0 + wA * wv0; z0 = (z0 > 0.f) ? z0 : 0.2f * z0;
            float z1 = hsA1 + hd1 + wA * wv1; z1 = (z1 > 0.f) ? z1 : 0.2f * z1;
            float t0 = z0 * a0, t1 = z1 * a1;
#pragma unroll
            for (int o = 16; o >= 1; o >>= 1) {
                t0 += __shfl_xor(t0, o);
                t1 += __shfl_xor(t1, o);
            }
            float mn0 = fmaxf(m0, t0), mn1 = fmaxf(m1, t1);
            float sc0 = __expf(m0 - mn0), sc1 = __expf(m1 - mn1);
            float p0 = __expf(t0 - mn0), p1 = __expf(t1 - mn1);
            l0 = l0 * sc0 + p0; acc0 = acc0 * sc0 + p0 * hsA0; m0 = mn0;
            l1 = l1 * sc1 + p1; acc1 = acc1 * sc1 + p1 * hsA1; m1 = mn1;
            // rotate
            hsA0 = hsB0; hsA1 = hsB1; wA = wB;
            hsB0 = hsC0; hsB1 = hsC1; wB = wC;
        }
    }
    out[(size_t)node * 128 + lane] = acc0 / (l0 + 1e-16f) + bias[lane];
    out[(size_t)node * 128 + 64 + lane] = acc1 / (l1 + 1e-16f) + bias[lane + 64];
}

// ---- combine + ELU + LayerNorm (in-place on d_out holding h_pruned) ----
__global__ __launch_bounds__(256) void final_kernel(const float* __restrict__ hf,
                                                    float* __restrict__ out,
                                                    const float* __restrict__ alpha_p,
                                                    const float* __restrict__ scale,
                                                    const float* __restrict__ beta, int n) {
    int node = blockIdx.x * 4 + (threadIdx.x >> 6);
    if (node >= n) return;
    int lane = threadIdx.x & 63;
    float a = *alpha_p;
    float f0 = hf[(size_t)node * 128 + lane], f1 = hf[(size_t)node * 128 + 64 + lane];
    float p0 = out[(size_t)node * 128 + lane], p1 = out[(size_t)node * 128 + 64 + lane];
    float x0 = (1.f - a) * f0 + a * p0;
    float x1 = (1.f - a) * f1 + a * p1;
    x0 = (x0 > 0.f) ? x0 : expm1f(x0);
    x1 = (x1 > 0.f) ? x1 : expm1f(x1);
    float sm = x0 + x1;
#pragma unroll
    for (int o = 32; o >= 1; o >>= 1) sm += __shfl_xor(sm, o);
    float mu = sm * (1.f / 128.f);
    float d0 = x0 - mu, d1 = x1 - mu;
    float v = d0 * d0 + d1 * d1;
#pragma unroll
    for (int o = 32; o >= 1; o >>= 1) v += __shfl_xor(v, o);
    float rstd = rsqrtf(v * (1.f / 128.f) + 1e-6f);
    out[(size_t)node * 128 + lane] = d0 * rstd * scale[lane] + beta[lane];
    out[(size_t)node * 128 + 64 + lane] = d1 * rstd * scale[lane + 64] + beta[lane + 64];
}

extern "C" void kernel_launch(void* const* d_in, const int* in_sizes, int n_in,
                              void* d_out, int out_size, void* d_ws, size_t ws_size,
                              hipStream_t stream) {
    const float* nf = (const float*)d_in[0];
    const int* fei = (const int*)d_in[1];
    const float* few = (const float*)d_in[2];
    const int* pei = (const int*)d_in[3];
    const float* pew = (const float*)d_in[4];
    const float* alpha = (const float*)d_in[5];
    const float* ip_w = (const float*)d_in[6];
    const float* ip_b = (const float*)d_in[7];
    const float* gf_wsrc = (const float*)d_in[8];
    const float* gf_wdst = (const float*)d_in[9];
    const float* gf_wedge = (const float*)d_in[10];
    const float* gf_attn = (const float*)d_in[11];
    const float* gf_bias = (const float*)d_in[12];
    const float* gp_wsrc = (const float*)d_in[13];
    const float* gp_wdst = (const float*)d_in[14];
    const float* gp_wedge = (const float*)d_in[15];
    const float* gp_attn = (const float*)d_in[16];
    const float* gp_bias = (const float*)d_in[17];
    const float* ln_scale = (const float*)d_in[18];
    const float* ln_bias = (const float*)d_in[19];

    const int N = in_sizes[0] / N_GENES;
    const int Ef = in_sizes[1] / 2;
    const int Ep = in_sizes[3] / 2;
    const int Etot = Ef + Ep;
    const int Kpad1 = 2048;
    const int n2 = 2 * N;

    char* base = (char*)d_ws;
    size_t off = 0;
    auto carve = [&](size_t bytes) -> char* {
        char* p = base + off;
        off = (off + bytes + 255) & ~(size_t)255;
        return p;
    };
    unsigned short* Bt1 = (unsigned short*)carve((size_t)128 * Kpad1 * 2);
    unsigned short* Bf = (unsigned short*)carve(256 * 128 * 2);
    unsigned short* Bp = (unsigned short*)carve(256 * 128 * 2);
    unsigned short* h_bf = (unsigned short*)carve((size_t)N * 128 * 2);
    unsigned short* hshd_f = (unsigned short*)carve((size_t)N * 256 * 2);
    unsigned short* hshd_p = (unsigned short*)carve((size_t)N * 256 * 2);
    float* h_full = (float*)carve((size_t)N * 128 * 4);
    int* deg = (int*)carve((size_t)n2 * 4);
    int* offs = (int*)carve((size_t)(n2 + 4) * 4);
    int* cur = (int*)carve((size_t)n2 * 4);
    int* bsum = (int*)carve(256 * 4);
    int* srcs = (int*)carve((size_t)Etot * 4);
    float* wso = (float*)carve((size_t)Etot * 4);
    float* out_f = (float*)d_out;

    // weight prep
    transpose_bt<<<(128 * Kpad1 + 255) / 256, 256, 0, stream>>>(ip_w, Bt1, N_GENES, Kpad1);
    transpose_small<<<(2 * 256 * 128 + 255) / 256, 256, 0, stream>>>(gf_wsrc, gf_wdst, gp_wsrc, gp_wdst, Bf, Bp);

    // h = nf @ ip_w + ip_b -> bf16
    int gb1 = (N + 63) / 64;
    gemm64<1, 128, 1><<<gb1, 256, 0, stream>>>(nf, Bt1, ip_b, h_bf, N, N_GENES, Kpad1);
    // [hs|hd] per graph, bf16
    gemm64<0, 256, 0><<<gb1, 256, 0, stream>>>(h_bf, Bf, nullptr, hshd_f, N, 128, 128);
    gemm64<0, 256, 0><<<gb1, 256, 0, stream>>>(h_bf, Bp, nullptr, hshd_p, N, 128, 128);

    // CSR for both graphs (concatenated degree array)
    const int* src_f = fei;
    const int* dst_f = fei + Ef;
    const int* src_p = pei;
    const int* dst_p = pei + Ep;
    hipMemsetAsync(deg, 0, (size_t)n2 * 4, stream);
    deg2<<<(Etot + 255) / 256, 256, 0, stream>>>(dst_f, Ef, dst_p, Ep, deg, N);
    int nb = (n2 + 2047) / 2048;
    scan_part<<<nb, 256, 0, stream>>>(deg, bsum, n2);
    scan_tops<<<1, 256, 0, stream>>>(bsum, nb, offs, n2);
    scan_final<<<nb, 256, 0, stream>>>(deg, bsum, offs, n2);
    hipMemsetAsync(cur, 0, (size_t)n2 * 4, stream);
    fill2<<<(Etot + 255) / 256, 256, 0, stream>>>(src_f, dst_f, few, Ef, src_p, dst_p, pew, Ep,
                                                  offs, cur, srcs, wso, N);

    // GAT both graphs
    int nodeblocks = (N + 3) / 4;
    gat_kernel<<<nodeblocks, 256, 0, stream>>>(offs, srcs, wso, hshd_f,
                                               gf_wedge, gf_attn, gf_bias, h_full, N);
    gat_kernel<<<nodeblocks, 256, 0, stream>>>(offs + N, srcs, wso, hshd_p,
                                               gp_wedge, gp_attn, gp_bias, out_f, N);

    final_kernel<<<nodeblocks, 256, 0, stream>>>(h_full, out_f, alpha, ln_scale, ln_bias, N);
    (void)ws_size; (void)n_in; (void)out_size;
}

// Round 3
// 915.628 us; speedup vs baseline: 1.2683x; 1.0626x over previous
//
#include <hip/hip_runtime.h>
#include <hip/hip_bf16.h>

#define N_GENES 2000
#define SA 72

typedef __attribute__((ext_vector_type(8))) short frag8;
typedef __attribute__((ext_vector_type(4))) float facc4;

static __device__ __forceinline__ unsigned short f2bf(float f) {
    unsigned int u = __float_as_uint(f);
    unsigned int r = (u + 0x7FFFu + ((u >> 16) & 1u)) >> 16;
    return (unsigned short)r;
}
static __device__ __forceinline__ float bf2f(unsigned short s) {
    return __uint_as_float(((unsigned int)s) << 16);
}
static __device__ __forceinline__ ushort2 pk2(float a, float b) {
    __hip_bfloat162 r = __float22bfloat162_rn(float2{a, b});
    return *(ushort2*)&r;
}

// ---- all weight transposes in one kernel ----
// ip_w [2000][128] -> Bt1 [128][2048] bf16 (zero-pad); per graph [wsrc|wdst] -> B [256][128] bf16
__global__ void prep(const float* __restrict__ ip_w,
                     const float* __restrict__ ws_f, const float* __restrict__ wd_f,
                     const float* __restrict__ ws_p, const float* __restrict__ wd_p,
                     unsigned short* __restrict__ Bt1,
                     unsigned short* __restrict__ Bf, unsigned short* __restrict__ Bp) {
    int idx = blockIdx.x * blockDim.x + threadIdx.x;
    if (idx < 128 * 2048) {
        int nrow = idx >> 11, k = idx & 2047;
        unsigned short v = 0;
        if (k < N_GENES) v = f2bf(ip_w[(size_t)k * 128 + nrow]);
        Bt1[idx] = v;
    } else {
        int q = idx - 128 * 2048;
        if (q >= 2 * 256 * 128) return;
        int g = q >> 15;
        int r = (q >> 7) & 255;
        int k = q & 127;
        const float* w = (g == 0) ? (r < 128 ? ws_f : wd_f) : (r < 128 ? ws_p : wd_p);
        (g == 0 ? Bf : Bp)[(r << 7) | k] = f2bf(w[k * 128 + (r & 127)]);
    }
}

// ---- GEMM1: C[M][128] = fp32 A[M][2000] @ ip_w, bf16 MFMA, A-only LDS, B frags from L2 ----
__global__ __launch_bounds__(256) void gemm1(const float* __restrict__ A,
                                             const unsigned short* __restrict__ Bt,
                                             const float* __restrict__ bias,
                                             unsigned short* __restrict__ Cb, int M, int K) {
    const int Kpad = 2048;
    __shared__ __align__(16) unsigned short lA[64 * SA];
    int t = threadIdx.x, lane = t & 63, wv = t >> 6;
    int lr = lane & 15, lq = lane >> 4;
    facc4 acc[4][2];
#pragma unroll
    for (int i = 0; i < 4; i++)
#pragma unroll
        for (int j = 0; j < 2; j++) acc[i][j] = (facc4){0.f, 0.f, 0.f, 0.f};
    int row_base = blockIdx.x * 64;

    // A staging coords: 16 threads per row, 16B each
    int ar_r[4], ar_c[4];
    const float* ar_p[4];
#pragma unroll
    for (int j = 0; j < 4; j++) {
        int q = j * 256 + t;
        ar_r[j] = q >> 4;
        ar_c[j] = (q & 15) * 4;
        int rg = row_base + ar_r[j];
        if (rg >= M) rg = M - 1;
        ar_p[j] = A + (size_t)rg * K + ar_c[j];
    }
    // B fragment pointers (col-major bf16 [128][2048], L2-resident)
    const unsigned short* bp[4];
#pragma unroll
    for (int ks = 0; ks < 2; ks++)
#pragma unroll
        for (int ni = 0; ni < 2; ni++) {
            int col = wv * 32 + ni * 16 + lr;
            bp[ks * 2 + ni] = Bt + (size_t)col * Kpad + ks * 32 + lq * 8;
        }

    float4 ar[4];
    frag8 bfr[4];
#pragma unroll
    for (int j = 0; j < 4; j++) ar[j] = *(const float4*)(ar_p[j]);
#pragma unroll
    for (int f = 0; f < 4; f++) bfr[f] = *(const frag8*)(bp[f]);

    for (int k0 = 0; k0 < Kpad; k0 += 64) {
        __syncthreads();
#pragma unroll
        for (int j = 0; j < 4; j++) {
            ushort2 u01 = pk2(ar[j].x, ar[j].y);
            ushort2 u23 = pk2(ar[j].z, ar[j].w);
            ushort4 u = {u01.x, u01.y, u23.x, u23.y};
            *(ushort4*)&lA[ar_r[j] * SA + ar_c[j]] = u;
        }
        __syncthreads();
        int kn = k0 + 64;
        frag8 bfn[4];
        if (kn < Kpad) {
#pragma unroll
            for (int j = 0; j < 4; j++) {
                int kk = kn + ar_c[j];
                float4 v = {0.f, 0.f, 0.f, 0.f};
                if (kk < K) v = *(const float4*)(ar_p[j] + kn);
                ar[j] = v;
            }
#pragma unroll
            for (int f = 0; f < 4; f++) bfn[f] = *(const frag8*)(bp[f] + kn);
        }
#pragma unroll
        for (int ks = 0; ks < 2; ks++) {
            frag8 af[4];
#pragma unroll
            for (int mi = 0; mi < 4; mi++)
                af[mi] = *(const frag8*)&lA[(mi * 16 + lr) * SA + ks * 32 + lq * 8];
#pragma unroll
            for (int mi = 0; mi < 4; mi++)
#pragma unroll
                for (int ni = 0; ni < 2; ni++)
                    acc[mi][ni] = __builtin_amdgcn_mfma_f32_16x16x32_bf16(af[mi], bfr[ks * 2 + ni], acc[mi][ni], 0, 0, 0);
        }
        if (kn < Kpad) {
#pragma unroll
            for (int f = 0; f < 4; f++) bfr[f] = bfn[f];
        }
    }
#pragma unroll
    for (int mi = 0; mi < 4; mi++) {
#pragma unroll
        for (int r = 0; r < 4; r++) {
            int row = row_base + mi * 16 + lq * 4 + r;
            if (row < M) {
#pragma unroll
                for (int ni = 0; ni < 2; ni++) {
                    int col = wv * 32 + ni * 16 + lr;
                    Cb[(size_t)row * 128 + col] = f2bf(acc[mi][ni][r] + bias[col]);
                }
            }
        }
    }
}

// ---- hshd GEMM: [hs|hd] = h_bf @ B[256][128], one dispatch for both graphs (blockIdx.y) ----
__global__ __launch_bounds__(256) void gemm_hshd(const unsigned short* __restrict__ A,
                                                 const unsigned short* __restrict__ Bf,
                                                 const unsigned short* __restrict__ Bp,
                                                 unsigned short* __restrict__ Cf,
                                                 unsigned short* __restrict__ Cp, int M) {
    const int K = 128, NT = 256, CF = 4;
    const unsigned short* Bt = blockIdx.y ? Bp : Bf;
    unsigned short* Cb = blockIdx.y ? Cp : Cf;
    __shared__ __align__(16) unsigned short lA[64 * SA];
    __shared__ __align__(16) unsigned short lB[NT * SA];
    int t = threadIdx.x, lane = t & 63, wv = t >> 6;
    int lr = lane & 15, lq = lane >> 4;
    facc4 acc[4][CF];
#pragma unroll
    for (int i = 0; i < 4; i++)
#pragma unroll
        for (int j = 0; j < CF; j++) acc[i][j] = (facc4){0.f, 0.f, 0.f, 0.f};
    int row_base = blockIdx.x * 64;

    for (int k0 = 0; k0 < K; k0 += 64) {
        __syncthreads();
#pragma unroll
        for (int j = 0; j < 2; j++) {
            int q = j * 256 + t;
            int r = q >> 3, off = (q & 7) * 8;
            int rg = row_base + r; if (rg >= M) rg = M - 1;
            *(uint4*)&lA[r * SA + off] = *(const uint4*)(A + (size_t)rg * K + k0 + off);
        }
#pragma unroll
        for (int j = 0; j < 8; j++) {
            int q = j * 256 + t;
            int r = q >> 3, off = (q & 7) * 8;
            *(uint4*)&lB[r * SA + off] = *(const uint4*)(Bt + (size_t)r * K + k0 + off);
        }
        __syncthreads();
#pragma unroll
        for (int ks = 0; ks < 2; ks++) {
            frag8 af[4], bf[CF];
#pragma unroll
            for (int mi = 0; mi < 4; mi++)
                af[mi] = *(const frag8*)&lA[(mi * 16 + lr) * SA + ks * 32 + lq * 8];
#pragma unroll
            for (int ni = 0; ni < CF; ni++)
                bf[ni] = *(const frag8*)&lB[(wv * 16 * CF + ni * 16 + lr) * SA + ks * 32 + lq * 8];
#pragma unroll
            for (int mi = 0; mi < 4; mi++)
#pragma unroll
                for (int ni = 0; ni < CF; ni++)
                    acc[mi][ni] = __builtin_amdgcn_mfma_f32_16x16x32_bf16(af[mi], bf[ni], acc[mi][ni], 0, 0, 0);
        }
    }
#pragma unroll
    for (int mi = 0; mi < 4; mi++) {
#pragma unroll
        for (int r = 0; r < 4; r++) {
            int row = row_base + mi * 16 + lq * 4 + r;
            if (row < M) {
#pragma unroll
                for (int ni = 0; ni < CF; ni++) {
                    int col = wv * 16 * CF + ni * 16 + lr;
                    Cb[(size_t)row * NT + col] = f2bf(acc[mi][ni][r]);
                }
            }
        }
    }
}

// ---- degree histogram for both graphs into deg[2N] ----
__global__ void deg2(const int* __restrict__ dst_f, int Ef,
                     const int* __restrict__ dst_p, int Ep,
                     int* __restrict__ deg, int N) {
    int e = blockIdx.x * blockDim.x + threadIdx.x;
    if (e < Ef) atomicAdd(&deg[dst_f[e]], 1);
    else if (e < Ef + Ep) atomicAdd(&deg[N + dst_p[e - Ef]], 1);
}

// ---- hierarchical exclusive scan ----
__global__ __launch_bounds__(256) void scan_part(const int* __restrict__ in,
                                                 int* __restrict__ bsum, int n) {
    int t = threadIdx.x, b = blockIdx.x;
    int lane = t & 63, wv = t >> 6;
    int base = b * 2048 + t * 8;
    int s = 0;
    if (base + 7 < n) {
        int4 v0 = *(const int4*)(in + base);
        int4 v1 = *(const int4*)(in + base + 4);
        s = v0.x + v0.y + v0.z + v0.w + v1.x + v1.y + v1.z + v1.w;
    } else {
#pragma unroll
        for (int j = 0; j < 8; j++) if (base + j < n) s += in[base + j];
    }
#pragma unroll
    for (int o = 32; o >= 1; o >>= 1) s += __shfl_xor(s, o);
    __shared__ int red[4];
    if (lane == 0) red[wv] = s;
    __syncthreads();
    if (t == 0) bsum[b] = red[0] + red[1] + red[2] + red[3];
}

__global__ __launch_bounds__(256) void scan_tops(int* __restrict__ bsum, int nb,
                                                 int* __restrict__ offs, int n) {
    __shared__ int buf[256];
    int t = threadIdx.x;
    int orig = (t < nb) ? bsum[t] : 0;
    int v = orig;
    buf[t] = v;
    __syncthreads();
    for (int o = 1; o < 256; o <<= 1) {
        int y = (t >= o) ? buf[t - o] : 0;
        __syncthreads();
        v += y;
        buf[t] = v;
        __syncthreads();
    }
    if (t < nb) bsum[t] = v - orig;
    if (t == nb - 1) offs[n] = v;
}

__global__ __launch_bounds__(256) void scan_final(const int* __restrict__ in,
                                                  const int* __restrict__ bsum,
                                                  int* __restrict__ offs, int n) {
    int t = threadIdx.x, b = blockIdx.x;
    int lane = t & 63, wv = t >> 6;
    int base = b * 2048 + t * 8;
    int a[8];
#pragma unroll
    for (int j = 0; j < 8; j++) a[j] = (base + j < n) ? in[base + j] : 0;
    int s = a[0] + a[1] + a[2] + a[3] + a[4] + a[5] + a[6] + a[7];
    int incl = s;
#pragma unroll
    for (int o = 1; o < 64; o <<= 1) {
        int y = __shfl_up(incl, o);
        if (lane >= o) incl += y;
    }
    __shared__ int wsum[4];
    if (lane == 63) wsum[wv] = incl;
    __syncthreads();
    int wpre = 0;
#pragma unroll
    for (int j = 0; j < 4; j++) if (j < wv) wpre += wsum[j];
    int excl = incl - s + wpre + bsum[b];
#pragma unroll
    for (int j = 0; j < 8; j++) {
        if (base + j < n) offs[base + j] = excl;
        excl += a[j];
    }
}

// ---- fill CSR-ordered (src, weight) int2 pairs; decrements deg in place (no cur array) ----
__global__ void fill2(const int* __restrict__ src_f, const int* __restrict__ dst_f,
                      const float* __restrict__ ew_f, int Ef,
                      const int* __restrict__ src_p, const int* __restrict__ dst_p,
                      const float* __restrict__ ew_p, int Ep,
                      const int* __restrict__ offs, int* __restrict__ deg,
                      int2* __restrict__ srcw, int N) {
    int e = blockIdx.x * blockDim.x + threadIdx.x;
    if (e >= Ef + Ep) return;
    int g = (e >= Ef);
    int ee = g ? e - Ef : e;
    int d = g ? dst_p[ee] : dst_f[ee];
    int node = g ? N + d : d;
    int p = offs[node] + atomicAdd(&deg[node], -1) - 1;
    int s = g ? src_p[ee] : src_f[ee];
    float w = g ? ew_p[ee] : ew_f[ee];
    srcw[p] = make_int2(s, __float_as_int(w));
}

// ---- GAT: one wave per dst node, both graphs in one dispatch, 2-edge ILP pipeline ----
__global__ __launch_bounds__(256) void gat2(const int* __restrict__ offs,
                                            const int2* __restrict__ srcw,
                                            const unsigned short* __restrict__ hshd_f,
                                            const unsigned short* __restrict__ hshd_p,
                                            const float* __restrict__ wedge_f,
                                            const float* __restrict__ attn_f,
                                            const float* __restrict__ bias_f,
                                            const float* __restrict__ wedge_p,
                                            const float* __restrict__ attn_p,
                                            const float* __restrict__ bias_p,
                                            float* __restrict__ out_full,
                                            float* __restrict__ out_pruned, int N) {
    int node = blockIdx.x * 4 + (threadIdx.x >> 6);
    if (node >= 2 * N) return;
    int g = node >= N;
    int onode = g ? node - N : node;
    const unsigned short* hshd = g ? hshd_p : hshd_f;
    const float* wedge = g ? wedge_p : wedge_f;
    const float* attn = g ? attn_p : attn_f;
    const float* bias = g ? bias_p : bias_f;
    float* out = g ? out_pruned : out_full;
    int lane = threadIdx.x & 63;
    const float wv0 = wedge[lane], wv1 = wedge[lane + 64];
    const float a0 = attn[lane], a1 = attn[lane + 64];
    const float hd0 = bf2f(hshd[(size_t)onode * 256 + 128 + lane]);
    const float hd1 = bf2f(hshd[(size_t)onode * 256 + 192 + lane]);
    int s = offs[node], cnt = offs[node + 1] - s;
    float m0 = -INFINITY, l0 = 0.f, acc0 = 0.f;
    float m1 = -INFINITY, l1 = 0.f, acc1 = 0.f;
    if (cnt > 0) {
        int last = s + cnt - 1;
        auto CL = [last](int j) { return j > last ? last : j; };
        int2 e0 = srcw[s], e1 = srcw[CL(s + 1)], e2 = srcw[CL(s + 2)], e3 = srcw[CL(s + 3)];
        float h00 = bf2f(hshd[(size_t)e0.x * 256 + lane]);
        float h01 = bf2f(hshd[(size_t)e0.x * 256 + 64 + lane]);
        float h10 = bf2f(hshd[(size_t)e1.x * 256 + lane]);
        float h11 = bf2f(hshd[(size_t)e1.x * 256 + 64 + lane]);
        float h20 = bf2f(hshd[(size_t)e2.x * 256 + lane]);
        float h21 = bf2f(hshd[(size_t)e2.x * 256 + 64 + lane]);
        float h30 = bf2f(hshd[(size_t)e3.x * 256 + lane]);
        float h31 = bf2f(hshd[(size_t)e3.x * 256 + 64 + lane]);
        for (int i = 0; i < cnt; i += 2) {
            int2 e4 = srcw[CL(s + i + 4)], e5 = srcw[CL(s + i + 5)];
            float h40 = bf2f(hshd[(size_t)e4.x * 256 + lane]);
            float h41 = bf2f(hshd[(size_t)e4.x * 256 + 64 + lane]);
            float h50 = bf2f(hshd[(size_t)e5.x * 256 + lane]);
            float h51 = bf2f(hshd[(size_t)e5.x * 256 + 64 + lane]);
            float w0 = __int_as_float(e0.y), w1 = __int_as_float(e1.y);
            float z00 = h00 + hd0 + w0 * wv0; z00 = (z00 > 0.f) ? z00 : 0.2f * z00;
            float z01 = h01 + hd1 + w0 * wv1; z01 = (z01 > 0.f) ? z01 : 0.2f * z01;
            float z10 = h10 + hd0 + w1 * wv0; z10 = (z10 > 0.f) ? z10 : 0.2f * z10;
            float z11 = h11 + hd1 + w1 * wv1; z11 = (z11 > 0.f) ? z11 : 0.2f * z11;
            float t00 = z00 * a0, t01 = z01 * a1;
            float t10 = z10 * a0, t11 = z11 * a1;
#pragma unroll
            for (int o = 16; o >= 1; o >>= 1) {
                t00 += __shfl_xor(t00, o);
                t01 += __shfl_xor(t01, o);
                t10 += __shfl_xor(t10, o);
                t11 += __shfl_xor(t11, o);
            }
            {
                float mn0 = fmaxf(m0, t00), mn1 = fmaxf(m1, t01);
                float sc0 = __expf(m0 - mn0), sc1 = __expf(m1 - mn1);
                float p0 = __expf(t00 - mn0), p1 = __expf(t01 - mn1);
                l0 = l0 * sc0 + p0; acc0 = acc0 * sc0 + p0 * h00; m0 = mn0;
                l1 = l1 * sc1 + p1; acc1 = acc1 * sc1 + p1 * h01; m1 = mn1;
            }
            if (i + 1 < cnt) {
                float mn0 = fmaxf(m0, t10), mn1 = fmaxf(m1, t11);
                float sc0 = __expf(m0 - mn0), sc1 = __expf(m1 - mn1);
                float p0 = __expf(t10 - mn0), p1 = __expf(t11 - mn1);
                l0 = l0 * sc0 + p0; acc0 = acc0 * sc0 + p0 * h10; m0 = mn0;
                l1 = l1 * sc1 + p1; acc1 = acc1 * sc1 + p1 * h11; m1 = mn1;
            }
            e0 = e2; h00 = h20; h01 = h21;
            e1 = e3; h10 = h30; h11 = h31;
            e2 = e4; h20 = h40; h21 = h41;
            e3 = e5; h30 = h50; h31 = h51;
        }
    }
    out[(size_t)onode * 128 + lane] = acc0 / (l0 + 1e-16f) + bias[lane];
    out[(size_t)onode * 128 + 64 + lane] = acc1 / (l1 + 1e-16f) + bias[lane + 64];
}

// ---- combine + ELU + LayerNorm (in-place on d_out holding h_pruned) ----
__global__ __launch_bounds__(256) void final_kernel(const float* __restrict__ hf,
                                                    float* __restrict__ out,
                                                    const float* __restrict__ alpha_p,
                                                    const float* __restrict__ scale,
                                                    const float* __restrict__ beta, int n) {
    int node = blockIdx.x * 4 + (threadIdx.x >> 6);
    if (node >= n) return;
    int lane = threadIdx.x & 63;
    float a = *alpha_p;
    float f0 = hf[(size_t)node * 128 + lane], f1 = hf[(size_t)node * 128 + 64 + lane];
    float p0 = out[(size_t)node * 128 + lane], p1 = out[(size_t)node * 128 + 64 + lane];
    float x0 = (1.f - a) * f0 + a * p0;
    float x1 = (1.f - a) * f1 + a * p1;
    x0 = (x0 > 0.f) ? x0 : expm1f(x0);
    x1 = (x1 > 0.f) ? x1 : expm1f(x1);
    float sm = x0 + x1;
#pragma unroll
    for (int o = 32; o >= 1; o >>= 1) sm += __shfl_xor(sm, o);
    float mu = sm * (1.f / 128.f);
    float d0 = x0 - mu, d1 = x1 - mu;
    float v = d0 * d0 + d1 * d1;
#pragma unroll
    for (int o = 32; o >= 1; o >>= 1) v += __shfl_xor(v, o);
    float rstd = rsqrtf(v * (1.f / 128.f) + 1e-6f);
    out[(size_t)node * 128 + lane] = d0 * rstd * scale[lane] + beta[lane];
    out[(size_t)node * 128 + 64 + lane] = d1 * rstd * scale[lane + 64] + beta[lane + 64];
}

extern "C" void kernel_launch(void* const* d_in, const int* in_sizes, int n_in,
                              void* d_out, int out_size, void* d_ws, size_t ws_size,
                              hipStream_t stream) {
    const float* nf = (const float*)d_in[0];
    const int* fei = (const int*)d_in[1];
    const float* few = (const float*)d_in[2];
    const int* pei = (const int*)d_in[3];
    const float* pew = (const float*)d_in[4];
    const float* alpha = (const float*)d_in[5];
    const float* ip_w = (const float*)d_in[6];
    const float* ip_b = (const float*)d_in[7];
    const float* gf_wsrc = (const float*)d_in[8];
    const float* gf_wdst = (const float*)d_in[9];
    const float* gf_wedge = (const float*)d_in[10];
    const float* gf_attn = (const float*)d_in[11];
    const float* gf_bias = (const float*)d_in[12];
    const float* gp_wsrc = (const float*)d_in[13];
    const float* gp_wdst = (const float*)d_in[14];
    const float* gp_wedge = (const float*)d_in[15];
    const float* gp_attn = (const float*)d_in[16];
    const float* gp_bias = (const float*)d_in[17];
    const float* ln_scale = (const float*)d_in[18];
    const float* ln_bias = (const float*)d_in[19];

    const int N = in_sizes[0] / N_GENES;
    const int Ef = in_sizes[1] / 2;
    const int Ep = in_sizes[3] / 2;
    const int Etot = Ef + Ep;
    const int n2 = 2 * N;

    char* base = (char*)d_ws;
    size_t off = 0;
    auto carve = [&](size_t bytes) -> char* {
        char* p = base + off;
        off = (off + bytes + 255) & ~(size_t)255;
        return p;
    };
    unsigned short* Bt1 = (unsigned short*)carve((size_t)128 * 2048 * 2);
    unsigned short* Bf = (unsigned short*)carve(256 * 128 * 2);
    unsigned short* Bp = (unsigned short*)carve(256 * 128 * 2);
    unsigned short* h_bf = (unsigned short*)carve((size_t)N * 128 * 2);
    unsigned short* hshd_f = (unsigned short*)carve((size_t)N * 256 * 2);
    unsigned short* hshd_p = (unsigned short*)carve((size_t)N * 256 * 2);
    float* h_full = (float*)carve((size_t)N * 128 * 4);
    int* deg = (int*)carve((size_t)n2 * 4);
    int* offs = (int*)carve((size_t)(n2 + 4) * 4);
    int* bsum = (int*)carve(256 * 4);
    int2* srcw = (int2*)carve((size_t)Etot * 8);
    float* out_f = (float*)d_out;

    prep<<<(128 * 2048 + 2 * 256 * 128 + 255) / 256, 256, 0, stream>>>(
        ip_w, gf_wsrc, gf_wdst, gp_wsrc, gp_wdst, Bt1, Bf, Bp);

    int gb1 = (N + 63) / 64;
    gemm1<<<gb1, 256, 0, stream>>>(nf, Bt1, ip_b, h_bf, N, N_GENES);
    gemm_hshd<<<dim3(gb1, 2), 256, 0, stream>>>(h_bf, Bf, Bp, hshd_f, hshd_p, N);

    const int* src_f = fei;
    const int* dst_f = fei + Ef;
    const int* src_p = pei;
    const int* dst_p = pei + Ep;
    hipMemsetAsync(deg, 0, (size_t)n2 * 4, stream);
    deg2<<<(Etot + 255) / 256, 256, 0, stream>>>(dst_f, Ef, dst_p, Ep, deg, N);
    int nb = (n2 + 2047) / 2048;
    scan_part<<<nb, 256, 0, stream>>>(deg, bsum, n2);
    scan_tops<<<1, 256, 0, stream>>>(bsum, nb, offs, n2);
    scan_final<<<nb, 256, 0, stream>>>(deg, bsum, offs, n2);
    fill2<<<(Etot + 255) / 256, 256, 0, stream>>>(src_f, dst_f, few, Ef, src_p, dst_p, pew, Ep,
                                                  offs, deg, srcw, N);

    gat2<<<(n2 + 3) / 4, 256, 0, stream>>>(offs, srcw, hshd_f, hshd_p,
                                           gf_wedge, gf_attn, gf_bias,
                                           gp_wedge, gp_attn, gp_bias,
                                           h_full, out_f, N);

    final_kernel<<<(N + 3) / 4, 256, 0, stream>>>(h_full, out_f, alpha, ln_scale, ln_bias, N);
    (void)ws_size; (void)n_in; (void)out_size;
}